// Round 17
// baseline (128.569 us; speedup 1.0000x reference)
//
#include <hip/hip_runtime.h>

#define Bn 4
#define Qn 1024
#define Kn 1024
#define Dd 256
#define Hh 64
#define Dv 256
#define TQ 16

typedef __attribute__((ext_vector_type(8))) short short8;
typedef __attribute__((ext_vector_type(4))) float floatx4;
typedef __attribute__((ext_vector_type(2))) float floatx2;

__device__ __forceinline__ floatx2 fma2(floatx2 a, floatx2 b, floatx2 c) {
    return __builtin_elementwise_fma(a, b, c);
}
__device__ __forceinline__ floatx2 mk2(float x, float y) {
    floatx2 r; r.x = x; r.y = y; return r;
}

__device__ __forceinline__ short f32_to_bf16(float x) {
    unsigned u = __float_as_uint(x);
    unsigned r = u + 0x7fffu + ((u >> 16) & 1u);   // RNE
    return (short)(r >> 16);
}
__device__ __forceinline__ float bf16_to_f32(short h) {
    return __uint_as_float(((unsigned)(unsigned short)h) << 16);
}

// Fused prep v2: proj at 2 rows/wave over 1024 blocks (4096 independent
// waves ≈ 17 waves/CU — R15's 512-block/4-row layout was latency-bound at
// ~10 waves/CU, prep ≈ 24us). V-swizzle unchanged.
//  blocks 0..1023   : projections (Eq + transposed Ekt, exp-folded)
//  blocks 1024..1151: V -> split-bf16 MFMA-A-fragment swizzle
__global__ __launch_bounds__(256) void prep_kernel(const float* __restrict__ Xq,
                                                   const float* __restrict__ Wq,
                                                   const float* __restrict__ Xk,
                                                   const float* __restrict__ Wk,
                                                   const float* __restrict__ V,
                                                   float* __restrict__ Eq,
                                                   float* __restrict__ Ekt,
                                                   short* __restrict__ Vhi,
                                                   short* __restrict__ Vlo) {
    __shared__ float tile[32 * 261];
    int t = threadIdx.x;
    if (blockIdx.x < 1024) {
        int gw = blockIdx.x * 4 + (t >> 6);        // 0..4095
        int h = t & 63;
        int side = gw >> 11;                       // 0: q, 1: k
        int row0 = (gw & 2047) * 2;                // 2 rows per wave
        const float* X = side ? Xk : Xq;
        const float* W = side ? Wk : Wq;
        float a0 = 0.f, a1 = 0.f;
        for (int d4 = 0; d4 < Dd / 4; ++d4) {
            float w0 = W[(d4 * 4 + 0) * Hh + h];
            float w1 = W[(d4 * 4 + 1) * Hh + h];
            float w2 = W[(d4 * 4 + 2) * Hh + h];
            float w3 = W[(d4 * 4 + 3) * Hh + h];
            float4 x0 = ((const float4*)(X + (size_t)row0 * Dd))[d4];        // uniform
            float4 x1 = ((const float4*)(X + (size_t)(row0 + 1) * Dd))[d4];  // uniform
            a0 = fmaf(x0.x, w0, a0); a0 = fmaf(x0.y, w1, a0);
            a0 = fmaf(x0.z, w2, a0); a0 = fmaf(x0.w, w3, a0);
            a1 = fmaf(x1.x, w0, a1); a1 = fmaf(x1.y, w1, a1);
            a1 = fmaf(x1.z, w2, a1); a1 = fmaf(x1.w, w3, a1);
        }
        float ev0 = __expf(2.f * a0);
        float ev1 = __expf(2.f * a1);
        if (!side) {
            Eq[(size_t)row0 * Hh + h] = ev0;
            Eq[(size_t)(row0 + 1) * Hh + h] = ev1;
        } else {
            int b0 = row0 >> 10, k0 = row0 & 1023;
            int b1 = (row0 + 1) >> 10, k1 = (row0 + 1) & 1023;
            Ekt[((size_t)b0 * Hh + h) * Kn + k0] = ev0;
            Ekt[((size_t)b1 * Hh + h) * Kn + k1] = ev1;
        }
    } else {
        int blk = blockIdx.x - 1024;
        int b = blk >> 5;
        int kt = blk & 31;
        const float* Vg = V + (b * Kn + kt * 32) * Dv;
        for (int i = 0; i < 8; ++i) {
            int k = i * 4 + (t >> 6);
            int n4 = (t & 63) * 4;
            float4 v = *(const float4*)(Vg + k * Dv + n4);
            tile[k * 261 + n4 + 0] = v.x;
            tile[k * 261 + n4 + 1] = v.y;
            tile[k * 261 + n4 + 2] = v.z;
            tile[k * 261 + n4 + 3] = v.w;
        }
        __syncthreads();
        int wave = t >> 6, l = t & 63;
        int n_in = l & 15, kc = l >> 4;
        for (int p = 0; p < 4; ++p) {
            int nt = wave * 4 + p;
            int n = nt * 16 + n_in;
            short8 hi, lo;
            #pragma unroll
            for (int j = 0; j < 8; ++j) {
                float x = tile[(kc * 8 + j) * 261 + n];
                short hs = f32_to_bf16(x);
                hi[j] = hs;
                lo[j] = f32_to_bf16(x - bf16_to_f32(hs));
            }
            size_t base = (((size_t)(b * 32 + kt) * 16 + nt) * 512) + (size_t)l * 8;
            *(short8*)(Vhi + base) = hi;
            *(short8*)(Vlo + base) = lo;
        }
    }
}

// score(q,k) = W_sum - 2*sum_h w_h/(Eq_h*Ek_h+1); W_sum cancels in softmax.
// R15 attn verbatim (last-good): 4-way rcp grouping, compiler-scheduled
// scalar fp32 (pk builtins scalarize; forced pk asm NaN'd — hazard-unsafe).
// Bounded scores -> no max-subtraction; p = exp(-2s) fused into score phase.
__global__ __launch_bounds__(1024, 4) void attn_kernel(const float* __restrict__ Eq,
                                                       const float* __restrict__ Ekt,
                                                       const short* __restrict__ Vhi,
                                                       const short* __restrict__ Vlo,
                                                       const float* __restrict__ wv,
                                                       float* __restrict__ out) {
    __shared__ __align__(16) unsigned sc[TQ * 1028];   // 65.8 KB: P hi/lo shorts
    __shared__ float wsum[16 * TQ];
    __shared__ float rinv_s[TQ];

    int tid = threadIdx.x;
    int blk = blockIdx.x;
    // XCD swizzle: blk%8 = XCD; batch b pinned to XCDs {2b,2b+1}.
    int b = (blk & 7) >> 1;
    int tile = (blk >> 3) * 2 + (blk & 1);   // 0..63, bijective per batch
    int qbase = tile * TQ;

    // ---- score phase: thread owns k = tid; q-pairs packed as float2 ----
    const float* kb = Ekt + (size_t)b * Hh * Kn;
    const float* qp = Eq + (size_t)(b * Qn + qbase) * Hh;
    const float4* wv4 = (const float4*)wv;
    floatx2 s2[TQ / 2];
    #pragma unroll
    for (int i = 0; i < TQ / 2; ++i) { s2[i].x = 0.f; s2[i].y = 0.f; }

    float e0 = kb[0 * Kn + tid];
    float e1 = kb[1 * Kn + tid];
    float e2 = kb[2 * Kn + tid];
    float e3 = kb[3 * Kn + tid];
    floatx2 one2 = mk2(1.f, 1.f);
    for (int h4 = 0; h4 < Hh / 4; ++h4) {
        float n0, n1, n2, n3;
        if (h4 < Hh / 4 - 1) {                 // prefetch next iteration
            const float* kn = kb + (h4 + 1) * 4 * Kn;
            n0 = kn[0 * Kn + tid];
            n1 = kn[1 * Kn + tid];
            n2 = kn[2 * Kn + tid];
            n3 = kn[3 * Kn + tid];
        }
        float4 w4 = wv4[h4];                            // uniform -> s_load
        floatx2 e0s = mk2(e0, e0), e1s = mk2(e1, e1);
        floatx2 e2s = mk2(e2, e2), e3s = mk2(e3, e3);
        floatx2 wx = mk2(w4.x, w4.x), wy = mk2(w4.y, w4.y);
        floatx2 wz = mk2(w4.z, w4.z), ww = mk2(w4.w, w4.w);
        #pragma unroll
        for (int qq = 0; qq < TQ; qq += 2) {
            float4 qva = *(const float4*)(qp + qq * Hh + h4 * 4);        // s_load
            float4 qvb = *(const float4*)(qp + (qq + 1) * Hh + h4 * 4);  // s_load
            floatx2 A = fma2(mk2(qva.x, qvb.x), e0s, one2);
            floatx2 B = fma2(mk2(qva.y, qvb.y), e1s, one2);
            floatx2 C = fma2(mk2(qva.z, qvb.z), e2s, one2);
            floatx2 D = fma2(mk2(qva.w, qvb.w), e3s, one2);
            floatx2 AB = A * B;
            floatx2 CD = C * D;
            floatx2 ABCD = AB * CD;
            floatx2 NAB = fma2(wx, B, wy * A);
            floatx2 NCD = fma2(wz, D, ww * C);
            floatx2 NUM = fma2(NCD, AB, NAB * CD);
            floatx2 R = mk2(__builtin_amdgcn_rcpf(ABCD.x),
                            __builtin_amdgcn_rcpf(ABCD.y));
            s2[qq >> 1] = fma2(NUM, R, s2[qq >> 1]);
        }
        e0 = n0; e1 = n1; e2 = n2; e3 = n3;
    }

    // p = exp(-2s); write bf16 hi/lo b16; per-q wave partials.
    unsigned short* sp = (unsigned short*)sc;
    float part[TQ];
    #pragma unroll
    for (int q = 0; q < TQ; ++q) {
        float sq = (q & 1) ? s2[q >> 1].y : s2[q >> 1].x;
        float p = __expf(-2.f * sq);
        part[q] = p;
        short hs = f32_to_bf16(p);
        sp[q * 2056 + tid] = (unsigned short)hs;
        sp[q * 2056 + 1024 + tid] = (unsigned short)f32_to_bf16(p - bf16_to_f32(hs));
    }

    int wave = tid >> 6, lane = tid & 63;
    #pragma unroll
    for (int q = 0; q < TQ; ++q) {
        #pragma unroll
        for (int off = 32; off >= 1; off >>= 1)
            part[q] += __shfl_xor(part[q], off, 64);
    }
    if (lane == 0) {
        #pragma unroll
        for (int q = 0; q < TQ; ++q) wsum[wave * TQ + q] = part[q];
    }
    __syncthreads();

    {   // wave w finalizes row q=w: sum 16 per-wave partials
        float v = (lane < 16) ? wsum[lane * TQ + wave] : 0.f;
        v += __shfl_xor(v, 8, 64);
        v += __shfl_xor(v, 4, 64);
        v += __shfl_xor(v, 2, 64);
        v += __shfl_xor(v, 1, 64);
        if (lane == 0) rinv_s[wave] = 1.f / v;
    }
    __syncthreads();

    // ---- AV via MFMA: wave owns ntile = wave; all 16 q-cols live ----
    int qf = lane & 15, kc = lane >> 4;
    floatx4 acc = {0.f, 0.f, 0.f, 0.f};
    const char* scb = (const char*)sc;
    for (int kt = 0; kt < 32; ++kt) {
        short8 bhi = *(const short8*)(scb + qf * 4112 + kt * 64 + kc * 16);
        short8 blo = *(const short8*)(scb + qf * 4112 + 2048 + kt * 64 + kc * 16);
        size_t base = (((size_t)(b * 32 + kt) * 16 + wave) * 512) + (size_t)lane * 8;
        short8 ah = *(const short8*)(Vhi + base);
        short8 al = *(const short8*)(Vlo + base);
        acc = __builtin_amdgcn_mfma_f32_16x16x32_bf16(ah, bhi, acc, 0, 0, 0);
        acc = __builtin_amdgcn_mfma_f32_16x16x32_bf16(al, bhi, acc, 0, 0, 0);
        acc = __builtin_amdgcn_mfma_f32_16x16x32_bf16(ah, blo, acc, 0, 0, 0);
    }
    {
        float r = rinv_s[qf];
        float* ob = out + ((size_t)(b * Qn + qbase + qf)) * Dv + wave * 16 + kc * 4;
        float4 o = { acc[0] * r, acc[1] * r, acc[2] * r, acc[3] * r };
        *(float4*)ob = o;
    }
}

extern "C" void kernel_launch(void* const* d_in, const int* in_sizes, int n_in,
                              void* d_out, int out_size, void* d_ws, size_t ws_size,
                              hipStream_t stream) {
    const float* queries = (const float*)d_in[0];
    const float* keys    = (const float*)d_in[1];
    const float* values  = (const float*)d_in[2];
    const float* W_q     = (const float*)d_in[3];
    const float* W_k     = (const float*)d_in[4];
    const float* w_v     = (const float*)d_in[5];
    float* out = (float*)d_out;

    float* Eq  = (float*)d_ws;                 // [B*Q, H]      1 MB
    float* Ekt = Eq + Bn * Qn * Hh;            // [B, H, K]     1 MB
    short* Vhi = (short*)(Ekt + Bn * Kn * Hh); // frag-order    2 MB
    short* Vlo = Vhi + (size_t)Bn * Kn * Dv;   // frag-order    2 MB

    prep_kernel<<<1152, 256, 0, stream>>>(queries, W_q, keys, W_k, values,
                                          Eq, Ekt, Vhi, Vlo);
    attn_kernel<<<Bn * (Qn / TQ), 1024, 0, stream>>>(Eq, Ekt, Vhi, Vlo, w_v, out);
}

// Round 18
// 124.361 us; speedup vs baseline: 1.0338x; 1.0338x over previous
//
#include <hip/hip_runtime.h>

#define Bn 4
#define Qn 1024
#define Kn 1024
#define Dd 256
#define Hh 64
#define Dv 256
#define TQ 16

typedef __attribute__((ext_vector_type(8))) short short8;
typedef __attribute__((ext_vector_type(4))) float floatx4;
typedef __attribute__((ext_vector_type(2))) float floatx2;

__device__ __forceinline__ floatx2 fma2(floatx2 a, floatx2 b, floatx2 c) {
    return __builtin_elementwise_fma(a, b, c);
}
__device__ __forceinline__ floatx2 mk2(float x, float y) {
    floatx2 r; r.x = x; r.y = y; return r;
}

__device__ __forceinline__ short f32_to_bf16(float x) {
    unsigned u = __float_as_uint(x);
    unsigned r = u + 0x7fffu + ((u >> 16) & 1u);   // RNE
    return (short)(r >> 16);
}
__device__ __forceinline__ float bf16_to_f32(short h) {
    return __uint_as_float(((unsigned)(unsigned short)h) << 16);
}

// Fused prep v3: proj at 8 rows/wave (1024 waves, 8 independent FMA chains;
// W cache traffic = 1024 x 64KB = 64MB, 4x less than R17 — fully overlapped
// under the ~6.8us/CU VALU floor). V-swizzle unchanged.
//  blocks 0..255  : projections (Eq + transposed Ekt, exp-folded)
//  blocks 256..383: V -> split-bf16 MFMA-A-fragment swizzle
__global__ __launch_bounds__(256) void prep_kernel(const float* __restrict__ Xq,
                                                   const float* __restrict__ Wq,
                                                   const float* __restrict__ Xk,
                                                   const float* __restrict__ Wk,
                                                   const float* __restrict__ V,
                                                   float* __restrict__ Eq,
                                                   float* __restrict__ Ekt,
                                                   short* __restrict__ Vhi,
                                                   short* __restrict__ Vlo) {
    __shared__ float tile[32 * 261];
    int t = threadIdx.x;
    if (blockIdx.x < 256) {
        int gw = blockIdx.x * 4 + (t >> 6);        // 0..1023
        int h = t & 63;
        int side = gw >> 9;                        // 0: q, 1: k
        int row0 = (gw & 511) * 8;                 // 8 rows per wave
        const float* X = side ? Xk : Xq;
        const float* W = side ? Wk : Wq;
        float acc[8] = {0.f, 0.f, 0.f, 0.f, 0.f, 0.f, 0.f, 0.f};
        for (int d4 = 0; d4 < Dd / 4; ++d4) {
            float w0 = W[(d4 * 4 + 0) * Hh + h];   // coalesced, L1/L2-hot
            float w1 = W[(d4 * 4 + 1) * Hh + h];
            float w2 = W[(d4 * 4 + 2) * Hh + h];
            float w3 = W[(d4 * 4 + 3) * Hh + h];
            #pragma unroll
            for (int r = 0; r < 8; ++r) {
                float4 xv = ((const float4*)(X + (size_t)(row0 + r) * Dd))[d4]; // uniform
                acc[r] = fmaf(xv.x, w0, acc[r]);
                acc[r] = fmaf(xv.y, w1, acc[r]);
                acc[r] = fmaf(xv.z, w2, acc[r]);
                acc[r] = fmaf(xv.w, w3, acc[r]);
            }
        }
        #pragma unroll
        for (int r = 0; r < 8; ++r) {
            int row = row0 + r;
            float e = __expf(2.f * acc[r]);
            if (!side) {
                Eq[(size_t)row * Hh + h] = e;      // coalesced
            } else {
                int b = row >> 10, k = row & 1023;
                Ekt[((size_t)b * Hh + h) * Kn + k] = e;
            }
        }
    } else {
        int blk = blockIdx.x - 256;
        int b = blk >> 5;
        int kt = blk & 31;
        const float* Vg = V + (b * Kn + kt * 32) * Dv;
        for (int i = 0; i < 8; ++i) {
            int k = i * 4 + (t >> 6);
            int n4 = (t & 63) * 4;
            float4 v = *(const float4*)(Vg + k * Dv + n4);
            tile[k * 261 + n4 + 0] = v.x;
            tile[k * 261 + n4 + 1] = v.y;
            tile[k * 261 + n4 + 2] = v.z;
            tile[k * 261 + n4 + 3] = v.w;
        }
        __syncthreads();
        int wave = t >> 6, l = t & 63;
        int n_in = l & 15, kc = l >> 4;
        for (int p = 0; p < 4; ++p) {
            int nt = wave * 4 + p;
            int n = nt * 16 + n_in;
            short8 hi, lo;
            #pragma unroll
            for (int j = 0; j < 8; ++j) {
                float x = tile[(kc * 8 + j) * 261 + n];
                short hs = f32_to_bf16(x);
                hi[j] = hs;
                lo[j] = f32_to_bf16(x - bf16_to_f32(hs));
            }
            size_t base = (((size_t)(b * 32 + kt) * 16 + nt) * 512) + (size_t)l * 8;
            *(short8*)(Vhi + base) = hi;
            *(short8*)(Vlo + base) = lo;
        }
    }
}

// score(q,k) = W_sum - 2*sum_h w_h/(Eq_h*Ek_h+1); W_sum cancels in softmax.
// R15 attn verbatim (last-good): 4-way rcp grouping, compiler-scheduled
// scalar fp32 (pk builtins scalarize; forced pk asm NaN'd — hazard-unsafe).
// Bounded scores -> no max-subtraction; p = exp(-2s) fused into score phase.
__global__ __launch_bounds__(1024, 4) void attn_kernel(const float* __restrict__ Eq,
                                                       const float* __restrict__ Ekt,
                                                       const short* __restrict__ Vhi,
                                                       const short* __restrict__ Vlo,
                                                       const float* __restrict__ wv,
                                                       float* __restrict__ out) {
    __shared__ __align__(16) unsigned sc[TQ * 1028];   // 65.8 KB: P hi/lo shorts
    __shared__ float wsum[16 * TQ];
    __shared__ float rinv_s[TQ];

    int tid = threadIdx.x;
    int blk = blockIdx.x;
    // XCD swizzle: blk%8 = XCD; batch b pinned to XCDs {2b,2b+1}.
    int b = (blk & 7) >> 1;
    int tile = (blk >> 3) * 2 + (blk & 1);   // 0..63, bijective per batch
    int qbase = tile * TQ;

    // ---- score phase: thread owns k = tid; q-pairs packed as float2 ----
    const float* kb = Ekt + (size_t)b * Hh * Kn;
    const float* qp = Eq + (size_t)(b * Qn + qbase) * Hh;
    const float4* wv4 = (const float4*)wv;
    floatx2 s2[TQ / 2];
    #pragma unroll
    for (int i = 0; i < TQ / 2; ++i) { s2[i].x = 0.f; s2[i].y = 0.f; }

    float e0 = kb[0 * Kn + tid];
    float e1 = kb[1 * Kn + tid];
    float e2 = kb[2 * Kn + tid];
    float e3 = kb[3 * Kn + tid];
    floatx2 one2 = mk2(1.f, 1.f);
    for (int h4 = 0; h4 < Hh / 4; ++h4) {
        float n0, n1, n2, n3;
        if (h4 < Hh / 4 - 1) {                 // prefetch next iteration
            const float* kn = kb + (h4 + 1) * 4 * Kn;
            n0 = kn[0 * Kn + tid];
            n1 = kn[1 * Kn + tid];
            n2 = kn[2 * Kn + tid];
            n3 = kn[3 * Kn + tid];
        }
        float4 w4 = wv4[h4];                            // uniform -> s_load
        floatx2 e0s = mk2(e0, e0), e1s = mk2(e1, e1);
        floatx2 e2s = mk2(e2, e2), e3s = mk2(e3, e3);
        floatx2 wx = mk2(w4.x, w4.x), wy = mk2(w4.y, w4.y);
        floatx2 wz = mk2(w4.z, w4.z), ww = mk2(w4.w, w4.w);
        #pragma unroll
        for (int qq = 0; qq < TQ; qq += 2) {
            float4 qva = *(const float4*)(qp + qq * Hh + h4 * 4);        // s_load
            float4 qvb = *(const float4*)(qp + (qq + 1) * Hh + h4 * 4);  // s_load
            floatx2 A = fma2(mk2(qva.x, qvb.x), e0s, one2);
            floatx2 B = fma2(mk2(qva.y, qvb.y), e1s, one2);
            floatx2 C = fma2(mk2(qva.z, qvb.z), e2s, one2);
            floatx2 D = fma2(mk2(qva.w, qvb.w), e3s, one2);
            floatx2 AB = A * B;
            floatx2 CD = C * D;
            floatx2 ABCD = AB * CD;
            floatx2 NAB = fma2(wx, B, wy * A);
            floatx2 NCD = fma2(wz, D, ww * C);
            floatx2 NUM = fma2(NCD, AB, NAB * CD);
            floatx2 R = mk2(__builtin_amdgcn_rcpf(ABCD.x),
                            __builtin_amdgcn_rcpf(ABCD.y));
            s2[qq >> 1] = fma2(NUM, R, s2[qq >> 1]);
        }
        e0 = n0; e1 = n1; e2 = n2; e3 = n3;
    }

    // p = exp(-2s); write bf16 hi/lo b16; per-q wave partials.
    unsigned short* sp = (unsigned short*)sc;
    float part[TQ];
    #pragma unroll
    for (int q = 0; q < TQ; ++q) {
        float sq = (q & 1) ? s2[q >> 1].y : s2[q >> 1].x;
        float p = __expf(-2.f * sq);
        part[q] = p;
        short hs = f32_to_bf16(p);
        sp[q * 2056 + tid] = (unsigned short)hs;
        sp[q * 2056 + 1024 + tid] = (unsigned short)f32_to_bf16(p - bf16_to_f32(hs));
    }

    int wave = tid >> 6, lane = tid & 63;
    #pragma unroll
    for (int q = 0; q < TQ; ++q) {
        #pragma unroll
        for (int off = 32; off >= 1; off >>= 1)
            part[q] += __shfl_xor(part[q], off, 64);
    }
    if (lane == 0) {
        #pragma unroll
        for (int q = 0; q < TQ; ++q) wsum[wave * TQ + q] = part[q];
    }
    __syncthreads();

    {   // wave w finalizes row q=w: sum 16 per-wave partials
        float v = (lane < 16) ? wsum[lane * TQ + wave] : 0.f;
        v += __shfl_xor(v, 8, 64);
        v += __shfl_xor(v, 4, 64);
        v += __shfl_xor(v, 2, 64);
        v += __shfl_xor(v, 1, 64);
        if (lane == 0) rinv_s[wave] = 1.f / v;
    }
    __syncthreads();

    // ---- AV via MFMA: wave owns ntile = wave; all 16 q-cols live ----
    int qf = lane & 15, kc = lane >> 4;
    floatx4 acc = {0.f, 0.f, 0.f, 0.f};
    const char* scb = (const char*)sc;
    for (int kt = 0; kt < 32; ++kt) {
        short8 bhi = *(const short8*)(scb + qf * 4112 + kt * 64 + kc * 16);
        short8 blo = *(const short8*)(scb + qf * 4112 + 2048 + kt * 64 + kc * 16);
        size_t base = (((size_t)(b * 32 + kt) * 16 + wave) * 512) + (size_t)lane * 8;
        short8 ah = *(const short8*)(Vhi + base);
        short8 al = *(const short8*)(Vlo + base);
        acc = __builtin_amdgcn_mfma_f32_16x16x32_bf16(ah, bhi, acc, 0, 0, 0);
        acc = __builtin_amdgcn_mfma_f32_16x16x32_bf16(al, bhi, acc, 0, 0, 0);
        acc = __builtin_amdgcn_mfma_f32_16x16x32_bf16(ah, blo, acc, 0, 0, 0);
    }
    {
        float r = rinv_s[qf];
        float* ob = out + ((size_t)(b * Qn + qbase + qf)) * Dv + wave * 16 + kc * 4;
        float4 o = { acc[0] * r, acc[1] * r, acc[2] * r, acc[3] * r };
        *(float4*)ob = o;
    }
}

extern "C" void kernel_launch(void* const* d_in, const int* in_sizes, int n_in,
                              void* d_out, int out_size, void* d_ws, size_t ws_size,
                              hipStream_t stream) {
    const float* queries = (const float*)d_in[0];
    const float* keys    = (const float*)d_in[1];
    const float* values  = (const float*)d_in[2];
    const float* W_q     = (const float*)d_in[3];
    const float* W_k     = (const float*)d_in[4];
    const float* w_v     = (const float*)d_in[5];
    float* out = (float*)d_out;

    float* Eq  = (float*)d_ws;                 // [B*Q, H]      1 MB
    float* Ekt = Eq + Bn * Qn * Hh;            // [B, H, K]     1 MB
    short* Vhi = (short*)(Ekt + Bn * Kn * Hh); // frag-order    2 MB
    short* Vlo = Vhi + (size_t)Bn * Kn * Dv;   // frag-order    2 MB

    prep_kernel<<<384, 256, 0, stream>>>(queries, W_q, keys, W_k, values,
                                         Eq, Ekt, Vhi, Vlo);
    attn_kernel<<<Bn * (Qn / TQ), 1024, 0, stream>>>(Eq, Ekt, Vhi, Vlo, w_v, out);
}